// Round 3
// baseline (1140.406 us; speedup 1.0000x reference)
//
#include <hip/hip_runtime.h>

// Problem constants (from reference setup_inputs)
#define N_NODES 50000
#define N_EDGES 800000
#define XF 512
#define EF 64
#define UF 128
#define HS 1024
#define CIN 832           // 512 + 3*64 + 128
#define EPS_BN 1e-5f
#define NMB 392           // M row-blocks
#define M_PAD 50176       // 392 * 128  (GEMM row padding)
#define NSCAN 50176       // scan padding (== M_PAD, convenient)

typedef __bf16 bf16x8 __attribute__((ext_vector_type(8)));
typedef short s16x8 __attribute__((ext_vector_type(8)));
typedef short s16x4 __attribute__((ext_vector_type(4)));
typedef float f32x4 __attribute__((ext_vector_type(4)));

__device__ __forceinline__ short f2bf(float f) {
  unsigned u = __float_as_uint(f);
  u += 0x7FFFu + ((u >> 16) & 1u);   // round-to-nearest-even (finite inputs)
  return (short)(u >> 16);
}
__device__ __forceinline__ float bf2f(short s) {
  return __uint_as_float(((unsigned)(unsigned short)s) << 16);
}

// async global->LDS, 16B per lane; LDS dest must be uniform-base + lane*16
#define ASYNC_CP(gp, lp)                                                      \
  __builtin_amdgcn_global_load_lds(                                           \
      (__attribute__((address_space(1))) void*)(gp),                          \
      (__attribute__((address_space(3))) void*)(lp), 16, 0, 0)

// ---------------------------------------------------------------------------
// 1) Edge histogram over destination node (int atomics, 1 per edge)
// ---------------------------------------------------------------------------
__global__ void hist_kernel(const int* __restrict__ col,
                            int* __restrict__ hist) {
  int e = blockIdx.x * 256 + threadIdx.x;   // grid exactly E
  atomicAdd(&hist[col[e]], 1);
}

// ---------------------------------------------------------------------------
// 2) 3-phase exclusive scan over NSCAN counts
// ---------------------------------------------------------------------------
__global__ void scan1_kernel(const int* __restrict__ hist,
                             int* __restrict__ starts,
                             int* __restrict__ bsum) {
  __shared__ int tmp[256];
  int i = blockIdx.x * 256 + threadIdx.x;
  int v = hist[i];
  tmp[threadIdx.x] = v;
  __syncthreads();
#pragma unroll
  for (int o = 1; o < 256; o <<= 1) {
    int t = (threadIdx.x >= o) ? tmp[threadIdx.x - o] : 0;
    __syncthreads();
    tmp[threadIdx.x] += t;
    __syncthreads();
  }
  starts[i] = tmp[threadIdx.x] - v;   // exclusive
  if (threadIdx.x == 255) bsum[blockIdx.x] = tmp[255];
}

__global__ void scan2_kernel(const int* __restrict__ bsum,
                             int* __restrict__ boff) {
  __shared__ int tmp[256];
  int v = (threadIdx.x < NSCAN / 256) ? bsum[threadIdx.x] : 0;
  tmp[threadIdx.x] = v;
  __syncthreads();
#pragma unroll
  for (int o = 1; o < 256; o <<= 1) {
    int t = (threadIdx.x >= o) ? tmp[threadIdx.x - o] : 0;
    __syncthreads();
    tmp[threadIdx.x] += t;
    __syncthreads();
  }
  boff[threadIdx.x] = tmp[threadIdx.x] - v;
}

__global__ void scan3_kernel(int* __restrict__ starts,
                             const int* __restrict__ boff,
                             int* __restrict__ cursor) {
  int i = blockIdx.x * 256 + threadIdx.x;
  int s = starts[i] + boff[blockIdx.x];
  starts[i] = s;
  cursor[i] = s;
}

// ---------------------------------------------------------------------------
// 3) Placement: edge ids sorted (bucketed) by destination node
// ---------------------------------------------------------------------------
__global__ void place_kernel(const int* __restrict__ col,
                             int* __restrict__ cursor,
                             int* __restrict__ sortedEid) {
  int e = blockIdx.x * 256 + threadIdx.x;   // grid exactly E
  int c = col[e];
  int pos = atomicAdd(&cursor[c], 1);
  sortedEid[pos] = e;
}

// ---------------------------------------------------------------------------
// 4) Segmented reduce: one wave per node; lane = feature.
// ---------------------------------------------------------------------------
__global__ __launch_bounds__(256) void edge_reduce_kernel(
    const float* __restrict__ ea, const int* __restrict__ sortedEid,
    const int* __restrict__ hist, const int* __restrict__ starts,
    short* __restrict__ h) {
  int node = blockIdx.x * 4 + (threadIdx.x >> 6);   // grid 12500 -> node<50000
  int lane = threadIdx.x & 63;
  int deg = hist[node];
  int st = starts[node];
  float s = 0.f, mx = -3.0e38f;
  for (int i = 0; i < deg; ++i) {
    int e = sortedEid[st + i];
    float v = ea[(size_t)e * EF + lane];
    s += v;
    mx = fmaxf(mx, v);
  }
  size_t base = (size_t)node * CIN;
  h[base + 640 + lane] = f2bf(deg ? mx : 0.f);
  h[base + 704 + lane] = f2bf(deg ? s / (float)deg : 0.f);
  h[base + 768 + lane] = f2bf(s);
}

// ---------------------------------------------------------------------------
// 5) Assemble x / u[batch] columns of h (bf16), zero pad rows entirely
// ---------------------------------------------------------------------------
__global__ __launch_bounds__(256) void assemble_xu_kernel(
    const float* __restrict__ x, const float* __restrict__ u,
    const int* __restrict__ batch, short* __restrict__ h) {
  int n = blockIdx.x;
  int t = threadIdx.x;
  size_t base = (size_t)n * CIN;
  if (n >= N_NODES) {           // pad rows: zero all 832 cols
    if (t < 208) *(s16x4*)&h[base + 4 * t] = (s16x4){0, 0, 0, 0};
    return;
  }
  if (t < 128) {
    const float4 v = *(const float4*)&x[(size_t)n * XF + 4 * t];
    *(s16x4*)&h[base + 4 * t] =
        (s16x4){f2bf(v.x), f2bf(v.y), f2bf(v.z), f2bf(v.w)};
  } else if (t < 160) {
    int c = 4 * (t - 128);
    const float4 v = *(const float4*)&u[batch[n] * UF + c];
    *(s16x4*)&h[base + XF + c] =
        (s16x4){f2bf(v.x), f2bf(v.y), f2bf(v.z), f2bf(v.w)};
  }
}

// ---------------------------------------------------------------------------
// 6) fp32 -> bf16 weight cast
// ---------------------------------------------------------------------------
__global__ void cast_kernel(const float* __restrict__ w, short* __restrict__ o,
                            int n) {
  int i = blockIdx.x * 256 + threadIdx.x;
  if (i < n) o[i] = f2bf(w[i]);
}

// ---------------------------------------------------------------------------
// 7) GEMM: C[M,1024] = A[M,K] @ B[1024,K]^T + bias, bf16 in.
//    m97 structure (128x128 tile, BK=32), plus:
//    - XCD-swizzled 1D grid: all 8 nb of one mb run consecutively on the same
//      XCD -> A row-tile fetched ~once into that XCD's L2.
//    - LDS-staged epilogue: full-cacheline coalesced stores.
//    - Atomic-free BN stats partials: row = mb*2 + (wave&1).
// ---------------------------------------------------------------------------
template <bool BF16OUT>
__global__ __launch_bounds__(256) void gemm_bt(
    const short* __restrict__ A, const short* __restrict__ B,
    const float* __restrict__ bias, void* __restrict__ outp, int K,
    int M_store, float* __restrict__ partials) {
  __shared__ float csmem[64 * 128];          // 32 KB; first 16 KB double as aT/bT
  short* aT = (short*)csmem;                 // 128*32 shorts = 8 KB
  short* bT = aT + 128 * 32;                 // 8 KB

  const int tid = threadIdx.x;
  const int lane = tid & 63;
  const int wave = tid >> 6;
  // XCD-aware decode: blockIdx.x % 8 == XCD (round-robin heuristic)
  const int xcd = blockIdx.x & 7;
  const int s = blockIdx.x >> 3;
  const int mb = xcd + 8 * (s >> 3);   // same XCD keeps mb for 8 consecutive s
  const int nb = s & 7;
  const int m0 = mb * 128;
  const int n0 = nb * 128;
  const int wm = (wave & 1) * 64;
  const int wn = (wave >> 1) * 64;
  const int lm = lane & 15;
  const int lk8 = (lane >> 4) * 8;

  f32x4 acc[4][4];
#pragma unroll
  for (int i = 0; i < 4; ++i)
#pragma unroll
    for (int j = 0; j < 4; ++j) acc[i][j] = (f32x4){0.f, 0.f, 0.f, 0.f};

  const int q0 = tid;
  const int q1 = tid + 256;
  const short* ga0 = A + (size_t)(m0 + (q0 >> 2)) * K + (q0 & 3) * 8;
  const short* ga1 = A + (size_t)(m0 + (q1 >> 2)) * K + (q1 & 3) * 8;
  const short* gb0 = B + (size_t)(n0 + (q0 >> 2)) * K + (q0 & 3) * 8;
  const short* gb1 = B + (size_t)(n0 + (q1 >> 2)) * K + (q1 & 3) * 8;
  short* la0 = &aT[q0 * 8];
  short* la1 = &aT[q1 * 8];
  short* lb0 = &bT[q0 * 8];
  short* lb1 = &bT[q1 * 8];

  int aoff[4], boff[4];
#pragma unroll
  for (int t = 0; t < 4; ++t) {
    aoff[t] = (wm + t * 16 + lm) * 32 + lk8;
    boff[t] = (wn + t * 16 + lm) * 32 + lk8;
  }

  for (int k0 = 0; k0 < K; k0 += 32) {
    __syncthreads();
    ASYNC_CP(ga0 + k0, la0);
    ASYNC_CP(ga1 + k0, la1);
    ASYNC_CP(gb0 + k0, lb0);
    ASYNC_CP(gb1 + k0, lb1);
    __syncthreads();
    bf16x8 af[4], bfr[4];
#pragma unroll
    for (int t = 0; t < 4; ++t) {
      af[t] = __builtin_bit_cast(bf16x8, *(const s16x8*)&aT[aoff[t]]);
      bfr[t] = __builtin_bit_cast(bf16x8, *(const s16x8*)&bT[boff[t]]);
    }
#pragma unroll
    for (int i = 0; i < 4; ++i)
#pragma unroll
      for (int j = 0; j < 4; ++j)
        acc[i][j] = __builtin_amdgcn_mfma_f32_16x16x32_bf16(af[i], bfr[j],
                                                            acc[i][j], 0, 0, 0);
  }

  // ---- bias + BN stat partials (no atomics, no LDS) ----
  // C/D layout: col=lane&15, row=(lane>>4)*4+reg  [m89-verified]
#pragma unroll
  for (int j = 0; j < 4; ++j) {
    const int colg = n0 + wn + j * 16 + lm;
    const float bv = bias[colg];
    float cs = 0.f, cq = 0.f;
#pragma unroll
    for (int i = 0; i < 4; ++i) {
#pragma unroll
      for (int r = 0; r < 4; ++r) {
        const int row = m0 + wm + i * 16 + (lane >> 4) * 4 + r;
        float v = acc[i][j][r] + bv;
        acc[i][j][r] = v;
        if (row < N_NODES) { cs += v; cq += v * v; }
      }
    }
    cs += __shfl_xor(cs, 16);
    cs += __shfl_xor(cs, 32);
    cq += __shfl_xor(cq, 16);
    cq += __shfl_xor(cq, 32);
    if (lane < 16) {
      size_t prow = (size_t)(mb * 2 + (wave & 1)) * 2048;
      partials[prow + colg] = cs;
      partials[prow + 1024 + colg] = cq;
    }
  }

  // ---- LDS-staged coalesced store, two 64-row passes ----
#pragma unroll
  for (int p = 0; p < 2; ++p) {
    __syncthreads();
    if ((wave & 1) == p) {
#pragma unroll
      for (int i = 0; i < 4; ++i)
#pragma unroll
        for (int j = 0; j < 4; ++j)
#pragma unroll
          for (int r = 0; r < 4; ++r) {
            int lr = i * 16 + (lane >> 4) * 4 + r;
            int lc = wn + j * 16 + lm;
            csmem[lr * 128 + lc] = acc[i][j][r];
          }
    }
    __syncthreads();
    if (BF16OUT) {
#pragma unroll
      for (int inner = 0; inner < 4; ++inner) {
        int row = inner * 16 + wave * 4 + (lane >> 4);
        int g = lane & 15;
        const float4 v0 = *(const float4*)&csmem[row * 128 + g * 8];
        const float4 v1 = *(const float4*)&csmem[row * 128 + g * 8 + 4];
        s16x8 o = {f2bf(v0.x), f2bf(v0.y), f2bf(v0.z), f2bf(v0.w),
                   f2bf(v1.x), f2bf(v1.y), f2bf(v1.z), f2bf(v1.w)};
        int grow = m0 + p * 64 + row;
        if (grow < M_store)
          *(s16x8*)&((short*)outp)[(size_t)grow * HS + n0 + g * 8] = o;
      }
    } else {
#pragma unroll
      for (int inner = 0; inner < 2; ++inner) {
        int row = inner * 32 + wave * 8 + (lane >> 3);
        int g = lane & 7;
        int grow = m0 + p * 64 + row;
#pragma unroll
        for (int cseg = 0; cseg < 4; ++cseg) {
          float4 v = *(const float4*)&csmem[row * 128 + cseg * 32 + g * 4];
          if (grow < M_store)
            *(float4*)&((float*)outp)[(size_t)grow * HS + n0 + cseg * 32 +
                                      g * 4] = v;
        }
      }
    }
  }
}

// ---------------------------------------------------------------------------
// 8) BN finalize: reduce partials (784 rows x 2048) -> per-channel scale/shift
// ---------------------------------------------------------------------------
__global__ void finalize_kernel(const float* __restrict__ partials,
                                const float* __restrict__ gamma,
                                const float* __restrict__ beta,
                                float* __restrict__ scsh) {
  int c = blockIdx.x * 256 + threadIdx.x;   // grid 4 x 256 = 1024
  float s = 0.f, q = 0.f;
  for (int r = 0; r < 2 * NMB; ++r) {
    s += partials[(size_t)r * 2048 + c];
    q += partials[(size_t)r * 2048 + 1024 + c];
  }
  const float inv = 1.f / (float)N_NODES;
  float m = s * inv;
  float var = q * inv - m * m;              // biased var, matches reference
  float sc = gamma[c] / sqrtf(var + EPS_BN);
  scsh[c] = sc;
  scsh[HS + c] = beta[c] - m * sc;
}

// ---------------------------------------------------------------------------
// 9) BN apply (in place). bf16 variant adds ReLU (layer 1).
// ---------------------------------------------------------------------------
__global__ __launch_bounds__(256) void bn_relu_bf16_kernel(
    short* __restrict__ y, const float* __restrict__ scsh) {
  size_t base = (size_t)blockIdx.x * HS + threadIdx.x * 4;
  int c = threadIdx.x * 4;
  s16x4 v = *(s16x4*)&y[base];
  s16x4 o;
#pragma unroll
  for (int k = 0; k < 4; ++k) {
    float f = bf2f(v[k]) * scsh[c + k] + scsh[HS + c + k];
    o[k] = f2bf(fmaxf(f, 0.f));
  }
  *(s16x4*)&y[base] = o;
}

__global__ __launch_bounds__(256) void bn_f32_kernel(
    float* __restrict__ y, const float* __restrict__ scsh) {
  size_t base = (size_t)blockIdx.x * HS + threadIdx.x * 4;
  int c = threadIdx.x * 4;
  float4 v = *(float4*)&y[base];
  const float4 sc = *(const float4*)&scsh[c];
  const float4 sh = *(const float4*)&scsh[HS + c];
  v.x = v.x * sc.x + sh.x;
  v.y = v.y * sc.y + sh.y;
  v.z = v.z * sc.z + sh.z;
  v.w = v.w * sc.w + sh.w;
  *(float4*)&y[base] = v;
}

// ---------------------------------------------------------------------------
extern "C" void kernel_launch(void* const* d_in, const int* in_sizes, int n_in,
                              void* d_out, int out_size, void* d_ws,
                              size_t ws_size, hipStream_t stream) {
  const float* x = (const float*)d_in[0];
  const float* ea = (const float*)d_in[1];
  const float* u = (const float*)d_in[2];
  const float* w1 = (const float*)d_in[3];
  const float* b1 = (const float*)d_in[4];
  const float* g1 = (const float*)d_in[5];
  const float* be1 = (const float*)d_in[6];
  const float* w2 = (const float*)d_in[7];
  const float* b2 = (const float*)d_in[8];
  const float* g2 = (const float*)d_in[9];
  const float* be2 = (const float*)d_in[10];
  const int* ei = (const int*)d_in[11];
  const int* batch = (const int*)d_in[12];
  float* out = (float*)d_out;
  const int* col = ei + N_EDGES;   // edge_index[1]

  // ---- workspace layout ----
  char* ws = (char*)d_ws;
  int* hist = (int*)ws;                          // NSCAN
  int* bsum = hist + NSCAN;                      // 256
  // ---- end of zero region ----
  size_t zero_bytes = (size_t)((char*)(bsum + 256) - ws);
  float* scsh = (float*)(bsum + 256);            // 2048
  int* starts = (int*)(scsh + 2048);             // NSCAN
  int* cursor = starts + NSCAN;                  // NSCAN
  int* boff = cursor + NSCAN;                    // 256
  int* sortedEid = boff + 256;                   // N_EDGES
  float* partials = (float*)(sortedEid + N_EDGES);   // 784*2048 f32 (6.4 MB)
  char* hraw = (char*)(partials + (size_t)2 * NMB * 2048);
  short* h = (short*)(((uintptr_t)hraw + 255) & ~(uintptr_t)255);
  short* w1b = h + (size_t)M_PAD * CIN;
  short* w2b = w1b + (size_t)HS * CIN;
  short* y1 = w2b + (size_t)HS * HS;

  hipMemsetAsync(ws, 0, zero_bytes, stream);

  // edge bucketing
  hist_kernel<<<N_EDGES / 256, 256, 0, stream>>>(col, hist);
  scan1_kernel<<<NSCAN / 256, 256, 0, stream>>>(hist, starts, bsum);
  scan2_kernel<<<1, 256, 0, stream>>>(bsum, boff);
  scan3_kernel<<<NSCAN / 256, 256, 0, stream>>>(starts, boff, cursor);
  place_kernel<<<N_EDGES / 256, 256, 0, stream>>>(col, cursor, sortedEid);

  // h assembly
  assemble_xu_kernel<<<M_PAD, 256, 0, stream>>>(x, u, batch, h);
  edge_reduce_kernel<<<N_NODES / 4, 256, 0, stream>>>(ea, sortedEid, hist,
                                                      starts, h);
  cast_kernel<<<(HS * CIN + 255) / 256, 256, 0, stream>>>(w1, w1b, HS * CIN);
  cast_kernel<<<(HS * HS + 255) / 256, 256, 0, stream>>>(w2, w2b, HS * HS);

  // layer 1
  gemm_bt<true><<<8 * NMB, 256, 0, stream>>>(h, w1b, b1, y1, CIN, M_PAD,
                                             partials);
  finalize_kernel<<<4, 256, 0, stream>>>(partials, g1, be1, scsh);
  bn_relu_bf16_kernel<<<N_NODES, 256, 0, stream>>>(y1, scsh);

  // layer 2
  gemm_bt<false><<<8 * NMB, 256, 0, stream>>>(y1, w2b, b2, out, HS, N_NODES,
                                              partials);
  finalize_kernel<<<4, 256, 0, stream>>>(partials, g2, be2, scsh);
  bn_f32_kernel<<<N_NODES, 256, 0, stream>>>(out, scsh);
}